// Round 10
// baseline (286.444 us; speedup 1.0000x reference)
//
#include <hip/hip_runtime.h>

#define T_LEN  16384
#define LTAG   64
#define F_PER  14
#define CHUNK  16
#define NCHUNK (T_LEN / CHUNK)   // 1024 -> 4 blocks/CU (LDS-capped)
#define BOS_ID 0
#define EOS_ID 1
#define NREG   6
#define REGSZ  833334      // 6 x 833334 >= 5,000,000 ; 3.33 MB/region -> L2-resident (proven)
#define WARM   40          // forward warm-up (proven R5/R9)
#define WB     72          // backward warm-up (proven R5/R9)
#define ROWS_MAX (WARM + CHUNK + WB + 1)   // 129 em rows staged per block

typedef __attribute__((ext_vector_type(4))) int i4;

// workspace layout (bytes) -- only em remains; bp/aEnd/partial eliminated
static constexpr size_t EM_OFF = 0;                                 // float[T*64] 4 MB

// ---------------------------------------------------------------------------
// K1: emissions  em[t,l] = sum_f w[feat[t,l,f]]  (fp32)
// Unchanged control (~88-90us structural floor: 56M random-line L2 requests
// at ~1/cyc/CU; NREG=6 keeps regions L2-resident -- 10:108us 6:88us 3:118us).
// Block 0 zeroes out[0], which k_viterbi accumulates via fp32 atomics.
// ---------------------------------------------------------------------------
__global__ __launch_bounds__(256) void k_emissions(
    const int* __restrict__ idx, const float* __restrict__ w, float* __restrict__ em,
    float* __restrict__ out)
{
    __shared__ int sIdx[256 * F_PER];          // 14 KB
    const int tid = threadIdx.x;
    if (blockIdx.x == 0 && tid == 0) out[0] = 0.f;
    const int* g = idx + (size_t)blockIdx.x * (256 * F_PER);
    for (int x = tid * 4; x < 256 * F_PER; x += 1024)
        *(i4*)(sIdx + x) = __builtin_nontemporal_load((const i4*)(g + x));
    __syncthreads();
    int id[F_PER];
#pragma unroll
    for (int f = 0; f < F_PER; ++f) id[f] = sIdx[tid * F_PER + f];
    float sf[F_PER];
#pragma unroll
    for (int f = 0; f < F_PER; ++f) sf[f] = 0.f;
    for (int r = 0; r < NREG; ++r) {
        const int lo = r * REGSZ;
#pragma unroll
        for (int f = 0; f < F_PER; ++f)
            if ((unsigned)(id[f] - lo) < (unsigned)REGSZ) sf[f] += w[id[f]];
    }
    float s = 0.f;
#pragma unroll
    for (int f = 0; f < F_PER; f += 2) s += sf[f] + sf[f + 1];
    em[(size_t)blockIdx.x * 256 + tid] = s;
}

// ---------------------------------------------------------------------------
// K2: FUSED self-sufficient Viterbi. Per block: stage em window into LDS
// (kills the per-step global em load -- suspected ~1100cy/step stall behind
// R6's VALUBusy=31%), forward warm + (CHUNK+WB) bp steps with bp in LDS
// ONLY (no global bp round-trip), local final tag for tail blocks (warm
// additive constant cancels in argmax), local backtrack, path + fp64 score
// term -> single fp32 atomicAdd into out[0] (no fence: fences cost +20-40us
// in R4/R5/R7; plain device atomics are MALL-coherent without one).
// Eliminates k_backtrack + k_sfin and 2 launch boundaries (~17-20us each,
// measured via R6's +52us for +3 boundaries).
// LDS: 33KB em + 5.5KB bp + 0.25KB alpha = 38.9KB -> 4 blocks/CU.
// ---------------------------------------------------------------------------
__global__ __launch_bounds__(64, 1) void k_viterbi(
    const float* __restrict__ trans, const float* __restrict__ em,
    float* __restrict__ out)
{
    __shared__ __align__(16) float sem[ROWS_MAX * 64];               // 33 KB
    __shared__ __align__(16) unsigned char sbp[(CHUNK + WB) * 64];   // 5.5 KB
    __shared__ __align__(16) float sa[64];
    const int c = blockIdx.x;
    const int tid = threadIdx.x;                 // = state j
    const int t0 = c * CHUNK;
    int nsteps = (T_LEN - 1) - t0; if (nsteps > CHUNK) nsteps = CHUNK;
    int t_hi = t0 + nsteps + WB; if (t_hi > T_LEN - 1) t_hi = T_LEN - 1;
    const int tw = (t0 <= WARM) ? 0 : t0 - WARM;
    const int nrows = t_hi - tw + 1;             // em rows [tw, t_hi]

    // stage em window (coalesced float4; rows contiguous in global)
    const float* esrc = em + (size_t)tw * 64;
    for (int x = tid * 4; x < nrows * 64; x += 256)
        *(float4*)(sem + x) = *(const float4*)(esrc + x);

    float tr_[64];                               // T[i][tid], i = 0..63
#pragma unroll
    for (int i = 0; i < 64; ++i) tr_[i] = trans[i * 64 + tid];
#pragma unroll
    for (int i = 0; i < 64; ++i) asm volatile("" : "+v"(tr_[i]));  // pin (R6: remat)
    const float teos = trans[tid * 64 + EOS_ID];
    __syncthreads();

    // init: exact at t=0 for leading blocks, neutral warm otherwise
    float a = (t0 <= WARM) ? (tr_[BOS_ID] + sem[tid]) : sem[tid];   // row 0 = tw
    const float4* ap = (const float4*)sa;

    // warm steps t in (tw, t0]: no backpointers
    for (int t = tw + 1; t <= t0; ++t) {
        sa[tid] = a;
        const float e = sem[(t - tw) * 64 + tid];
        float m = -3.0e38f;
#pragma unroll
        for (int g = 0; g < 4; ++g) {
            const float4 v0 = ap[4*g+0], v1 = ap[4*g+1], v2 = ap[4*g+2], v3 = ap[4*g+3];
            float s0[16];
            s0[0]  = tr_[16*g+0]  + v0.x;  s0[1]  = tr_[16*g+1]  + v0.y;
            s0[2]  = tr_[16*g+2]  + v0.z;  s0[3]  = tr_[16*g+3]  + v0.w;
            s0[4]  = tr_[16*g+4]  + v1.x;  s0[5]  = tr_[16*g+5]  + v1.y;
            s0[6]  = tr_[16*g+6]  + v1.z;  s0[7]  = tr_[16*g+7]  + v1.w;
            s0[8]  = tr_[16*g+8]  + v2.x;  s0[9]  = tr_[16*g+9]  + v2.y;
            s0[10] = tr_[16*g+10] + v2.z;  s0[11] = tr_[16*g+11] + v2.w;
            s0[12] = tr_[16*g+12] + v3.x;  s0[13] = tr_[16*g+13] + v3.y;
            s0[14] = tr_[16*g+14] + v3.z;  s0[15] = tr_[16*g+15] + v3.w;
#pragma unroll
            for (int st = 8; st >= 1; st >>= 1)
#pragma unroll
                for (int i = 0; i < st; ++i) s0[i] = fmaxf(s0[i], s0[i + st]);
            m = fmaxf(m, s0[0]);
        }
        a = e + m;
    }

    // bp steps t in (t0, t_hi]: emit backpointers to LDS (row t-t0-1)
    for (int t = t0 + 1; t <= t_hi; ++t) {
        sa[tid] = a;
        const float e = sem[(t - tw) * 64 + tid];
        float m = -3.0e38f; int bi = 0;
#pragma unroll
        for (int g = 0; g < 4; ++g) {
            const float4 v0 = ap[4*g+0], v1 = ap[4*g+1], v2 = ap[4*g+2], v3 = ap[4*g+3];
            float s0[16];
            s0[0]  = tr_[16*g+0]  + v0.x;  s0[1]  = tr_[16*g+1]  + v0.y;
            s0[2]  = tr_[16*g+2]  + v0.z;  s0[3]  = tr_[16*g+3]  + v0.w;
            s0[4]  = tr_[16*g+4]  + v1.x;  s0[5]  = tr_[16*g+5]  + v1.y;
            s0[6]  = tr_[16*g+6]  + v1.z;  s0[7]  = tr_[16*g+7]  + v1.w;
            s0[8]  = tr_[16*g+8]  + v2.x;  s0[9]  = tr_[16*g+9]  + v2.y;
            s0[10] = tr_[16*g+10] + v2.z;  s0[11] = tr_[16*g+11] + v2.w;
            s0[12] = tr_[16*g+12] + v3.x;  s0[13] = tr_[16*g+13] + v3.y;
            s0[14] = tr_[16*g+14] + v3.z;  s0[15] = tr_[16*g+15] + v3.w;
            float t16[16];
#pragma unroll
            for (int i = 0; i < 16; ++i) t16[i] = s0[i];
#pragma unroll
            for (int st = 8; st >= 1; st >>= 1)
#pragma unroll
                for (int i = 0; i < st; ++i) t16[i] = fmaxf(t16[i], t16[i + st]);
            const float gm = t16[0];
            int gb = 15;                          // first index attaining gm
#pragma unroll
            for (int i = 14; i >= 0; --i) gb = (s0[i] == gm) ? i : gb;
            if (gm > m) { m = gm; bi = 16*g + gb; }   // strict > keeps first group
        }
        a = e + m;
        sbp[(t - t0 - 1) * 64 + tid] = (unsigned char)bi;
    }

    // final tag: only blocks whose window reached t=16383 need it (exact:
    // the warm additive constant cancels in the argmax). Others start at 0
    // and rely on backtrack-warm coalescence (proven WB).
    int start_tag = 0;
    if (t_hi == T_LEN - 1) {
        float val = a + teos;                    // a = alpha(16383) + const
        int idx = tid;
#pragma unroll
        for (int o = 32; o >= 1; o >>= 1) {
            float ov = __shfl_xor(val, o);
            int   oi = __shfl_xor(idx, o);
            if (ov > val || (ov == val && oi < idx)) { val = ov; idx = oi; }
        }
        start_tag = idx;
    }

    // walk down on LDS bp; all lanes follow the same tag (broadcast reads).
    int tag = start_tag, pp = 0, pt = 0;
    for (int t = t_hi; t > t0; --t) {
        const int r = t - t0;
        if (tid == r)     pp = tag;
        if (tid + 1 == r) pt = tag;
        tag = sbp[(r - 1) * 64 + tag];
    }
    if (tid == 0) pp = tag;                      // tag at t0

    // path writes
    if (tid < nsteps) out[1 + t0 + tid] = (float)pp;
    if (c == NCHUNK - 1 && tid == nsteps) out[1 + (T_LEN - 1)] = (float)pp;

    // exact fp64 score terms for t in (t0, t0+nsteps]
    double term = 0.0;
    if (tid < nsteps) {
        const int t = t0 + 1 + tid;
        term = (double)trans[pp * 64 + pt] + (double)sem[(t - tw) * 64 + pt];
    }
    if (c == 0 && tid == 0)
        term += (double)trans[BOS_ID * 64 + pp] + (double)sem[pp];
    if (c == NCHUNK - 1 && tid == nsteps)
        term += (double)trans[pp * 64 + EOS_ID];
#pragma unroll
    for (int o = 1; o < 64; o <<= 1) term += __shfl_xor(term, o);
    if (tid == 0) atomicAdd(out, (float)term);   // device atomic, NO fence
}

// ---------------------------------------------------------------------------
extern "C" void kernel_launch(void* const* d_in, const int* in_sizes, int n_in,
                              void* d_out, int out_size, void* d_ws, size_t ws_size,
                              hipStream_t stream)
{
    const int*   feat = (const int*)d_in[0];
    const float* w    = (const float*)d_in[1];
    const float* tr   = (const float*)d_in[2];
    float* out = (float*)d_out;
    char*  ws  = (char*)d_ws;

    float* em = (float*)(ws + EM_OFF);

    k_emissions <<<(T_LEN * LTAG) / 256, 256, 0, stream>>>(feat, w, em, out);
    k_viterbi   <<<NCHUNK, 64, 0, stream>>>(tr, em, out);
}

// Round 11
// 245.648 us; speedup vs baseline: 1.1661x; 1.1661x over previous
//
#include <hip/hip_runtime.h>

#define T_LEN  16384
#define LTAG   64
#define F_PER  14
#define CHUNK  8
#define NCHUNK (T_LEN / CHUNK)   // 2048 -> 8 blocks/CU = 2 waves/SIMD
#define BOS_ID 0
#define EOS_ID 1
#define NREG   6
#define REGSZ  833334      // 6 x 833334 >= 5,000,000 ; 3.33 MB/region -> L2-resident (proven)
#define WARM   40          // forward warm-up (proven R5/R9)
#define WB     72          // backward warm-up (proven R5/R9)

typedef __attribute__((ext_vector_type(4))) int i4;

// workspace layout (bytes)
static constexpr size_t EM_OFF = 0;                                 // float[T*64] 4 MB
static constexpr size_t BP_OFF = EM_OFF + (size_t)T_LEN * 64 * 4;   // uchar[T*64] 1 MB
static constexpr size_t AE_OFF = BP_OFF + (size_t)T_LEN * 64;       // float[64]
static constexpr size_t PS_OFF = AE_OFF + 512;                      // double[2048]

// ---------------------------------------------------------------------------
// K1: emissions  em[t,l] = sum_f w[feat[t,l,f]]  (fp32)
// At its L2-line roofline: 56M random gathers x 64B line fill L2->L1
// ~ 3.6GB @ ~34.5TB/s aggregate ~ 88us. NREG=6 keeps regions L2-resident.
// Control dispatch -- expected unchanged (~88-90us, FETCH ~188MB).
// ---------------------------------------------------------------------------
__global__ __launch_bounds__(256) void k_emissions(
    const int* __restrict__ idx, const float* __restrict__ w, float* __restrict__ em)
{
    __shared__ int sIdx[256 * F_PER];          // 14 KB
    const int tid = threadIdx.x;
    const int* g = idx + (size_t)blockIdx.x * (256 * F_PER);
    for (int x = tid * 4; x < 256 * F_PER; x += 1024)
        *(i4*)(sIdx + x) = __builtin_nontemporal_load((const i4*)(g + x));
    __syncthreads();
    int id[F_PER];
#pragma unroll
    for (int f = 0; f < F_PER; ++f) id[f] = sIdx[tid * F_PER + f];
    float sf[F_PER];
#pragma unroll
    for (int f = 0; f < F_PER; ++f) sf[f] = 0.f;
    for (int r = 0; r < NREG; ++r) {
        const int lo = r * REGSZ;
#pragma unroll
        for (int f = 0; f < F_PER; ++f)
            if ((unsigned)(id[f] - lo) < (unsigned)REGSZ) sf[f] += w[id[f]];
    }
    float s = 0.f;
#pragma unroll
    for (int f = 0; f < F_PER; f += 2) s += sf[f] + sf[f + 1];
    em[(size_t)blockIdx.x * 256 + tid] = s;
}

// ---------------------------------------------------------------------------
// K2: forward Viterbi, LDS-FREE recurrence. R10 proved the per-step cost is
// the LDS broadcast itself (em-in-LDS changed nothing; 16 ds_read_b128/step
// x 4-8 waves saturates the per-CU LDS pipe ~128B/clk -> ~500-1000cy/step,
// VALUBusy stuck at 31-36%). Alpha is now broadcast via v_readlane -- pure
// VALU, per-SIMD scaling, zero LDS in the loop. tr_ stays pinned in VGPRs
// (R6: VGPR_Count=52 proved remat; R1's slow readlane version ALSO re-read
// T from LDS per step and serialized the max chain -- both fixed here).
// No fences anywhere (R4/R5/R7 regression).
// ---------------------------------------------------------------------------
__global__ __launch_bounds__(64, 2) void k_phase3(
    const float* __restrict__ trans, const float* __restrict__ em,
    unsigned char* __restrict__ bp, float* __restrict__ aEnd)
{
    const int c = blockIdx.x;
    const int tid = threadIdx.x;                 // = state j
    const int t0 = c * CHUNK;
    int nsteps = (T_LEN - 1) - t0; if (nsteps > CHUNK) nsteps = CHUNK;

    float tr_[64];                               // T[i][tid], i = 0..63
#pragma unroll
    for (int i = 0; i < 64; ++i) tr_[i] = trans[i * 64 + tid];
#pragma unroll
    for (int i = 0; i < 64; ++i) asm volatile("" : "+v"(tr_[i]));  // pin (R6: remat)

    float a; int tw;
    if (t0 <= WARM) { tw = 0; a = tr_[BOS_ID] + em[tid]; }   // exact init at t=0
    else            { tw = t0 - WARM; a = em[(size_t)tw * 64 + tid]; } // neutral init

    // 4-deep emission prefetch queue (static indexing -> stays in VGPRs)
    #define EMROW(t) em[(size_t)((t) < T_LEN - 1 ? (t) : T_LEN - 1) * 64 + tid]
    float p0 = EMROW(tw + 1), p1 = EMROW(tw + 2), p2 = EMROW(tw + 3), p3 = EMROW(tw + 4);

    // warm (or exact-replay) steps: max only, no backpointers
    for (int t = tw + 1; t <= t0; ++t) {
        const float e = p0;
        p0 = p1; p1 = p2; p2 = p3; p3 = EMROW(t + 4);
        const unsigned au = __float_as_uint(a);
        float t4[16];
#pragma unroll
        for (int q = 0; q < 16; ++q) {
            const float a0 = __uint_as_float(__builtin_amdgcn_readlane(au, 4*q+0));
            const float a1 = __uint_as_float(__builtin_amdgcn_readlane(au, 4*q+1));
            const float a2 = __uint_as_float(__builtin_amdgcn_readlane(au, 4*q+2));
            const float a3 = __uint_as_float(__builtin_amdgcn_readlane(au, 4*q+3));
            t4[q] = fmaxf(fmaxf(tr_[4*q+0] + a0, tr_[4*q+1] + a1),
                          fmaxf(tr_[4*q+2] + a2, tr_[4*q+3] + a3));
        }
#pragma unroll
        for (int st = 8; st >= 1; st >>= 1)
#pragma unroll
            for (int i = 0; i < st; ++i) t4[i] = fmaxf(t4[i], t4[i + st]);
        a = e + t4[0];
    }

    // real steps: emit backpointers (first-max semantics = jnp.argmax)
    const int tend = t0 + nsteps;
    for (int t = t0 + 1; t <= tend; ++t) {
        const float e = p0;
        p0 = p1; p1 = p2; p2 = p3; p3 = EMROW(t + 4);
        const unsigned au = __float_as_uint(a);
        float m = -3.0e38f; int bi = 0;
#pragma unroll
        for (int g = 0; g < 4; ++g) {
            float s0[16];
#pragma unroll
            for (int i = 0; i < 16; ++i)
                s0[i] = tr_[16*g+i]
                      + __uint_as_float(__builtin_amdgcn_readlane(au, 16*g+i));
            float t16[16];
#pragma unroll
            for (int i = 0; i < 16; ++i) t16[i] = s0[i];
#pragma unroll
            for (int st = 8; st >= 1; st >>= 1)
#pragma unroll
                for (int i = 0; i < st; ++i) t16[i] = fmaxf(t16[i], t16[i + st]);
            const float gm = t16[0];
            int gb = 15;                          // first index attaining gm
#pragma unroll
            for (int i = 14; i >= 0; --i) gb = (s0[i] == gm) ? i : gb;
            if (gm > m) { m = gm; bi = 16*g + gb; }   // strict > keeps first group
        }
        a = e + m;
        bp[(size_t)t * 64 + tid] = (unsigned char)bi;
    }
    if (c == NCHUNK - 1) aEnd[tid] = a;          // alpha at t = 16383
    #undef EMROW
}

// ---------------------------------------------------------------------------
// K3: per-chunk warm backtrack -> path + EXACT fp64 score terms.
// Plain partial[] store; NO fence, NO ticket.
// ---------------------------------------------------------------------------
__global__ __launch_bounds__(64) void k_backtrack(
    const float* __restrict__ trans, const float* __restrict__ em,
    const unsigned char* __restrict__ bp, const float* __restrict__ aEnd,
    float* __restrict__ out, double* __restrict__ partial)
{
    __shared__ __align__(16) unsigned char sbp[(CHUNK + WB) * 64];   // 5 KB
    const int c = blockIdx.x;
    const int tid = threadIdx.x;
    const int t0 = c * CHUNK;
    int nsteps = (T_LEN - 1) - t0; if (nsteps > CHUNK) nsteps = CHUNK;
    int t_hi = t0 + nsteps + WB; if (t_hi > T_LEN - 1) t_hi = T_LEN - 1;
    const int nrows = t_hi - t0;                 // bp rows t0+1 .. t_hi

    // stage bp window into LDS (coalesced 16B loads)
    const unsigned char* gsrc = bp + (size_t)(t0 + 1) * 64;
    for (int x = tid * 16; x < nrows * 64; x += 1024)
        *(i4*)(sbp + x) = *(const i4*)(gsrc + x);

    // final tag: argmax_j aEnd[j] + T[j][EOS], first-occurrence tie-break
    float val = aEnd[tid] + trans[tid * 64 + EOS_ID];
    int idx = tid;
#pragma unroll
    for (int o = 32; o >= 1; o >>= 1) {
        float ov = __shfl_xor(val, o);
        int   oi = __shfl_xor(idx, o);
        if (ov > val || (ov == val && oi < idx)) { val = ov; idx = oi; }
    }
    __syncthreads();

    // walk down; all lanes follow the same tag (broadcast LDS reads).
    int tag = (t_hi == T_LEN - 1) ? idx : 0;
    int pp = 0, pt = 0;
    for (int t = t_hi; t > t0; --t) {
        const int r = t - t0;
        if (tid == r)     pp = tag;
        if (tid + 1 == r) pt = tag;
        tag = sbp[(r - 1) * 64 + tag];
    }
    if (tid == 0) pp = tag;                      // tag at t0

    // path writes
    if (tid < nsteps) out[1 + t0 + tid] = (float)pp;
    if (c == NCHUNK - 1 && tid == nsteps) out[1 + (T_LEN - 1)] = (float)pp;

    // exact fp64 score terms for t in (t0, t0+nsteps]
    double term = 0.0;
    if (tid < nsteps) {
        const int t = t0 + 1 + tid;
        term = (double)trans[pp * 64 + pt] + (double)em[(size_t)t * 64 + pt];
    }
    if (c == 0 && tid == 0)
        term += (double)trans[BOS_ID * 64 + pp] + (double)em[pp];
    if (c == NCHUNK - 1 && tid == nsteps)
        term += (double)trans[pp * 64 + EOS_ID];
#pragma unroll
    for (int o = 1; o < 64; o <<= 1) term += __shfl_xor(term, o);
    if (tid == 0) partial[c] = term;
}

// ---------------------------------------------------------------------------
// K4: reduce 2048 partials -> out[0]
// ---------------------------------------------------------------------------
__global__ __launch_bounds__(64) void k_sfin(
    const double* __restrict__ partial, float* __restrict__ out)
{
    const int tid = threadIdx.x;
    double s = 0.0;
    for (int k = tid; k < NCHUNK; k += 64) s += partial[k];
#pragma unroll
    for (int o = 1; o < 64; o <<= 1) s += __shfl_xor(s, o);
    if (tid == 0) out[0] = (float)s;
}

// ---------------------------------------------------------------------------
extern "C" void kernel_launch(void* const* d_in, const int* in_sizes, int n_in,
                              void* d_out, int out_size, void* d_ws, size_t ws_size,
                              hipStream_t stream)
{
    const int*   feat = (const int*)d_in[0];
    const float* w    = (const float*)d_in[1];
    const float* tr   = (const float*)d_in[2];
    float* out = (float*)d_out;
    char*  ws  = (char*)d_ws;

    float*         em = (float*)(ws + EM_OFF);
    unsigned char* bp = (unsigned char*)(ws + BP_OFF);
    float*         ae = (float*)(ws + AE_OFF);
    double*        ps = (double*)(ws + PS_OFF);

    k_emissions <<<(T_LEN * LTAG) / 256, 256, 0, stream>>>(feat, w, em);
    k_phase3    <<<NCHUNK, 64, 0, stream>>>(tr, em, bp, ae);
    k_backtrack <<<NCHUNK, 64, 0, stream>>>(tr, em, bp, ae, out, ps);
    k_sfin      <<<1,      64, 0, stream>>>(ps, out);
}